// Round 11
// baseline (143.155 us; speedup 1.0000x reference)
//
#include <hip/hip_runtime.h>

// Problem dims: B=16, Q=64, K=512, DQ=DK=DV=512, H=256
#define LOG2E 1.4426950408889634f
#define TWO_LOG2E 2.8853900817779268f

typedef __attribute__((ext_vector_type(8))) short short8;   // bf16x8 MFMA frag
typedef __attribute__((ext_vector_type(4))) float f32x4;    // MFMA acc

__device__ __forceinline__ float e2x(float v) {
    return __builtin_amdgcn_exp2f(v * TWO_LOG2E);   // e^{2v}
}

// Exact fp32 -> (hi,lo) bf16 split, packed.
__device__ __forceinline__ void split2(float x, float y, unsigned& hi, unsigned& lo) {
    unsigned ux = __float_as_uint(x), uy = __float_as_uint(y);
    float hx = __uint_as_float(ux & 0xffff0000u);
    float hy = __uint_as_float(uy & 0xffff0000u);
    unsigned lx = __float_as_uint(x - hx), ly = __float_as_uint(y - hy);
    hi = (ux >> 16) | (uy & 0xffff0000u);
    lo = (lx >> 16) | (ly & 0xffff0000u);
}

// ---------------------------------------------------------------------------
// Kernel 0: W2T split/transposed weights (unchanged)
// ---------------------------------------------------------------------------
__global__ __launch_bounds__(256) void wprep_kernel(const float* __restrict__ Wq,
                                                    const float* __restrict__ Wk,
                                                    ushort* __restrict__ Wq2T,
                                                    ushort* __restrict__ Wk2T) {
    __shared__ float T[64][65];
    const float* W  = blockIdx.z ? Wk : Wq;
    ushort* W2T     = blockIdx.z ? Wk2T : Wq2T;
    const int t  = threadIdx.x;
    const int k0 = blockIdx.x * 64;
    const int n0 = blockIdx.y * 64;
#pragma unroll
    for (int p = 0; p < 4; ++p) {
        int u  = t + p * 256;
        int kk = u >> 4;
        int nf = (u & 15) * 4;
        float4 w = *reinterpret_cast<const float4*>(&W[(size_t)(k0 + kk) * 256 + n0 + nf]);
        T[nf + 0][kk] = w.x; T[nf + 1][kk] = w.y;
        T[nf + 2][kk] = w.z; T[nf + 3][kk] = w.w;
    }
    __syncthreads();
#pragma unroll
    for (int p = 0; p < 4; ++p) {
        int u  = t + p * 256;
        int n  = u >> 4;
        int kf = (u & 15) * 4;
        float a = T[n][kf], b = T[n][kf + 1], c = T[n][kf + 2], d = T[n][kf + 3];
        unsigned h01, l01, h23, l23;
        split2(a, b, h01, l01);
        split2(c, d, h23, l23);
        int kg = k0 + kf;
        ushort* row = W2T + (size_t)(n0 + n) * 1536 + (kg >> 5) * 96 + (kg & 31);
        uint2 hi; hi.x = h01; hi.y = h23;
        uint2 lo; lo.x = l01; lo.y = l23;
        *reinterpret_cast<uint2*>(row)      = hi;
        *reinterpret_cast<uint2*>(row + 32) = hi;
        *reinterpret_cast<uint2*>(row + 64) = lo;
    }
}

// ---------------------------------------------------------------------------
// Kernel 1: fused MFMA projection (unchanged from round 10)
// ---------------------------------------------------------------------------
__global__ __launch_bounds__(256) void mfma_proj_kernel(const float* __restrict__ queries,
                                                        const float* __restrict__ keys,
                                                        const ushort* __restrict__ Wq2T,
                                                        const ushort* __restrict__ Wk2T,
                                                        float* __restrict__ Eq,
                                                        float* __restrict__ Ekp) {
    __shared__ float smemf[7680];
    ushort* Ah = reinterpret_cast<ushort*>(smemf);           // [32 m][96 k']
    ushort* Ws = reinterpret_cast<ushort*>(smemf) + 3072;    // [128 n][96 k']

    const int t    = threadIdx.x;
    const int mt   = blockIdx.x;
    const int Nb   = blockIdx.y * 128;
    const bool isQ = mt < 32;
    const int mloc = (isQ ? mt : mt - 32) * 32;
    const float4* Asrc4 = reinterpret_cast<const float4*>(isQ ? queries : keys)
                        + (size_t)mloc * 128;
    const ushort* W2T = isQ ? Wq2T : Wk2T;

    const int ln15 = t & 15;
    const int q    = (t >> 4) & 3;
    const int w    = t >> 6;
    const int wn   = w * 32;
    const int am   = t >> 3;
    const int ak   = t & 7;

    const char* gB[6];
#pragma unroll
    for (int i = 0; i < 6; ++i) {
        int o   = i * 4096 + t * 16;
        int row = o / 192;
        int rem = o - row * 192;
        gB[i] = reinterpret_cast<const char*>(W2T) + (size_t)(Nb + row) * 3072 + rem;
    }

    f32x4 acc[2][2];
#pragma unroll
    for (int fm = 0; fm < 2; ++fm)
#pragma unroll
        for (int fn = 0; fn < 2; ++fn) acc[fm][fn] = (f32x4)0.0f;

    float4 ra = Asrc4[(size_t)am * 128 + ak];

    for (int c = 0; c < 16; ++c) {
        __syncthreads();
#pragma unroll
        for (int i = 0; i < 6; ++i) {
            __builtin_amdgcn_global_load_lds(
                reinterpret_cast<const unsigned int*>(gB[i]),
                reinterpret_cast<unsigned int*>(
                    reinterpret_cast<char*>(Ah) + 6144 + i * 4096 + (t >> 6) * 1024),
                16, 0, 0);
            gB[i] += 192;
        }
        {
            unsigned h01, l01, h23, l23;
            split2(ra.x, ra.y, h01, l01);
            split2(ra.z, ra.w, h23, l23);
            uint2 hi; hi.x = h01; hi.y = h23;
            uint2 lo; lo.x = l01; lo.y = l23;
            ushort* row = Ah + am * 96 + ak * 4;
            *reinterpret_cast<uint2*>(row)      = hi;
            *reinterpret_cast<uint2*>(row + 32) = lo;
            *reinterpret_cast<uint2*>(row + 64) = hi;
        }
        if (c < 15) ra = Asrc4[(size_t)am * 128 + (c + 1) * 8 + ak];
        __syncthreads();
#pragma unroll
        for (int s = 0; s < 3; ++s) {
            short8 af[2], bf[2];
#pragma unroll
            for (int fm = 0; fm < 2; ++fm)
                af[fm] = *reinterpret_cast<const short8*>(
                    Ah + (fm * 16 + ln15) * 96 + s * 32 + q * 8);
#pragma unroll
            for (int fn = 0; fn < 2; ++fn)
                bf[fn] = *reinterpret_cast<const short8*>(
                    Ws + (wn + fn * 16 + ln15) * 96 + s * 32 + q * 8);
#pragma unroll
            for (int fm = 0; fm < 2; ++fm)
#pragma unroll
                for (int fn = 0; fn < 2; ++fn)
                    acc[fm][fn] = __builtin_amdgcn_mfma_f32_16x16x32_bf16(
                        af[fm], bf[fn], acc[fm][fn], 0, 0, 0);
        }
    }

    if (isQ) {
#pragma unroll
        for (int fm = 0; fm < 2; ++fm)
#pragma unroll
            for (int fn = 0; fn < 2; ++fn)
#pragma unroll
                for (int r = 0; r < 4; ++r) {
                    int row = mloc + fm * 16 + q * 4 + r;
                    int col = Nb + wn + fn * 16 + ln15;
                    Eq[(size_t)row * 256 + col] = e2x(acc[fm][fn][r]);
                }
    } else {
        __syncthreads();
        float (*Cs)[33] = reinterpret_cast<float(*)[33]>(smemf);  // [n 128][m 32]
#pragma unroll
        for (int fm = 0; fm < 2; ++fm)
#pragma unroll
            for (int fn = 0; fn < 2; ++fn)
#pragma unroll
                for (int r = 0; r < 4; ++r) {
                    int m_l = fm * 16 + q * 4 + r;
                    int n_l = wn + fn * 16 + ln15;
                    Cs[n_l][m_l] = acc[fm][fn][r];
                }
        __syncthreads();
        const int b      = mloc >> 9;
        const int k0h    = (mloc & 511) >> 1;
        const int h2base = Nb >> 1;
        float4* out4 = reinterpret_cast<float4*>(Ekp);
#pragma unroll
        for (int p = 0; p < 4; ++p) {
            int u   = t + p * 256;
            int h2r = u >> 4;
            int kp  = u & 15;
            int kk  = kp * 2;
            float4 o;
            o.x = e2x(Cs[2 * h2r    ][kk    ]);
            o.y = e2x(Cs[2 * h2r + 1][kk    ]);
            o.z = e2x(Cs[2 * h2r    ][kk + 1]);
            o.w = e2x(Cs[2 * h2r + 1][kk + 1]);
            out4[(size_t)b * 32768 + (size_t)(h2base + h2r) * 256 + k0h + kp] = o;
        }
    }
}

// ---------------------------------------------------------------------------
// Kernel 2 (REBUILT): raw masked scores, q-reuse 8x.
// Block = (b, 8q, 128k); grid (4, 8, 16) = 512 (2/CU).
// 256 thr = 128 k-lanes x 2 h-halves; Eq8[8][256] + Wv in LDS; per h2 one
// coalesced 8 B Ekp read serves all 8 q. Ekp traffic 256 MB -> 64 MB.
// h-half partials combined via LDS; masked scores written (softmax in pv).
// ---------------------------------------------------------------------------
__global__ __launch_bounds__(256) void score_raw_kernel(
        const float* __restrict__ Eq, const float* __restrict__ Ekp,
        const float* __restrict__ Wv, const int* __restrict__ valid_lens,
        float* __restrict__ scores) {
    __shared__ float Eqs[8][256];     // 8 KB
    __shared__ float Wvs[256];        // 1 KB
    __shared__ float Sh[2][8][128];   // 8 KB
    const int t  = threadIdx.x;
    const int kb = blockIdx.x * 128;
    const int q0 = blockIdx.y * 8;
    const int b  = blockIdx.z;

    const float4* eq4 = reinterpret_cast<const float4*>(Eq + (size_t)(b * 64 + q0) * 256);
#pragma unroll
    for (int i = 0; i < 2; ++i) {
        int u = t + i * 256;          // 0..511: row = u>>6, col4 = u&63
        *reinterpret_cast<float4*>(&Eqs[u >> 6][(u & 63) * 4]) = eq4[u];
    }
    Wvs[t] = Wv[t];
    __syncthreads();

    const int kl = t & 127;           // k_local
    const int hh = t >> 7;            // h-half
    // Ekp as float2 array: elem (h2, k) at index b*65536 + h2*512 + k
    const float2* ek2 = reinterpret_cast<const float2*>(Ekp)
                      + (size_t)b * 65536 + (size_t)hh * 32768 + kb + kl;

    float acc[8] = {0.f, 0.f, 0.f, 0.f, 0.f, 0.f, 0.f, 0.f};
#pragma unroll 4
    for (int i = 0; i < 64; ++i) {
        float2 ek = ek2[(size_t)i * 512];
        int h2 = hh * 64 + i;
        float w0 = Wvs[2 * h2], w1 = Wvs[2 * h2 + 1];
#pragma unroll
        for (int q = 0; q < 8; ++q) {
            float e0 = Eqs[q][2 * h2], e1 = Eqs[q][2 * h2 + 1];
            float a0 = fmaf(e0, ek.x, 1.0f);
            float a1 = fmaf(e1, ek.y, 1.0f);
            float d  = a0 * a1;
            float n  = fmaf(w1, a0, w0 * a1);
            acc[q] = fmaf(n, __builtin_amdgcn_rcpf(d), acc[q]);
        }
    }
#pragma unroll
    for (int q = 0; q < 8; ++q) Sh[hh][q][kl] = acc[q];
    __syncthreads();

    const int vl = valid_lens[b];
#pragma unroll
    for (int i = 0; i < 4; ++i) {
        int u = t + i * 256;          // 0..1023
        int q = u >> 7, k = u & 127;
        float s = -2.0f * (Sh[0][q][k] + Sh[1][q][k]);
        if (kb + k >= vl) s = -1e6f;
        scores[(size_t)(b * 64 + q0 + q) * 512 + kb + k] = s;
    }
}

// ---------------------------------------------------------------------------
// Kernel 3: softmax (fused, per-wave in LDS) + out = P @ values.
// Same structure as round 10 pv; Ps now holds raw scores, each wave
// softmaxes its own 2 rows after staging (no extra barrier needed).
// ---------------------------------------------------------------------------
__global__ __launch_bounds__(256) void pv_kernel(const float* __restrict__ scores,
                                                 const float* __restrict__ values,
                                                 float* __restrict__ out) {
    __shared__ __align__(16) float Ps[8][516];      // 16512 B
    __shared__ __align__(16) float Vs[2][32][128];  // 2 x 16384 B

    const int t  = threadIdx.x;
    const int b  = blockIdx.z;
    const int q0 = blockIdx.y * 8;
    const int vt = blockIdx.x;

    const float4* sc4 = reinterpret_cast<const float4*>(scores) + (size_t)(b * 64 + q0) * 128;
#pragma unroll
    for (int p = 0; p < 4; ++p) {
        int u  = t + p * 256;
        int qr = u >> 7;
        int c4 = u & 127;
        *reinterpret_cast<float4*>(&Ps[qr][c4 * 4]) = sc4[(size_t)qr * 128 + c4];
    }

    const char* vbase = reinterpret_cast<const char*>(values)
                      + ((size_t)b * 512 * 512 + (size_t)vt * 128) * 4
                      + (size_t)(t >> 5) * 2048 + (size_t)(t & 31) * 16;
    char* ldsV0 = reinterpret_cast<char*>(&Vs[0][0][0]) + (t >> 6) * 1024;

    const int lane = t & 63;
    const int w    = t >> 6;
    const int v4   = lane & 31;
    const int ksub = lane >> 5;

    // issue chunk 0 into buffer 0
#pragma unroll
    for (int i = 0; i < 4; ++i)
        __builtin_amdgcn_global_load_lds(
            reinterpret_cast<const unsigned int*>(vbase + (size_t)i * 8 * 2048),
            reinterpret_cast<unsigned int*>(ldsV0 + i * 4096), 16, 0, 0);
    __syncthreads();                             // Ps + chunk0 ready

    // ---- per-wave softmax on own rows (2w, 2w+1); no cross-wave sharing ----
#pragma unroll
    for (int rr = 0; rr < 2; ++rr) {
        const int r = 2 * w + rr;
        float v[8];
        float m = -1e30f;
#pragma unroll
        for (int i = 0; i < 8; ++i) { v[i] = Ps[r][lane + i * 64]; m = fmaxf(m, v[i]); }
#pragma unroll
        for (int off = 32; off > 0; off >>= 1) m = fmaxf(m, __shfl_xor(m, off));
        float s = 0.f;
#pragma unroll
        for (int i = 0; i < 8; ++i) {
            v[i] = __builtin_amdgcn_exp2f((v[i] - m) * LOG2E);
            s += v[i];
        }
#pragma unroll
        for (int off = 32; off > 0; off >>= 1) s += __shfl_xor(s, off);
        float inv = 1.0f / s;
#pragma unroll
        for (int i = 0; i < 8; ++i) Ps[r][lane + i * 64] = v[i] * inv;
    }

    float4 acc0 = make_float4(0.f, 0.f, 0.f, 0.f);
    float4 acc1 = make_float4(0.f, 0.f, 0.f, 0.f);

    for (int c = 0; c < 16; ++c) {
        if (c < 15) {
            char* dst = reinterpret_cast<char*>(&Vs[(c + 1) & 1][0][0]) + (t >> 6) * 1024;
            const char* src = vbase + (size_t)(c + 1) * 65536;
#pragma unroll
            for (int i = 0; i < 4; ++i)
                __builtin_amdgcn_global_load_lds(
                    reinterpret_cast<const unsigned int*>(src + (size_t)i * 8 * 2048),
                    reinterpret_cast<unsigned int*>(dst + i * 4096), 16, 0, 0);
        }

        const float (*V)[128] = Vs[c & 1];
        const float* pr0 = &Ps[2 * w][c * 32];
        const float* pr1 = &Ps[2 * w + 1][c * 32];
#pragma unroll
        for (int kk = 0; kk < 4; ++kk) {
            int kb = kk * 8 + ksub * 4;
            float4 V0 = *reinterpret_cast<const float4*>(&V[kb + 0][v4 * 4]);
            float4 V1 = *reinterpret_cast<const float4*>(&V[kb + 1][v4 * 4]);
            float4 V2 = *reinterpret_cast<const float4*>(&V[kb + 2][v4 * 4]);
            float4 V3 = *reinterpret_cast<const float4*>(&V[kb + 3][v4 * 4]);
            float4 p0 = *reinterpret_cast<const float4*>(&pr0[kb]);
            float4 p1 = *reinterpret_cast<const float4*>(&pr1[kb]);
            acc0.x = fmaf(p0.x, V0.x, acc0.x); acc0.y = fmaf(p0.x, V0.y, acc0.y);
            acc0.z = fmaf(p0.x, V0.z, acc0.z); acc0.w = fmaf(p0.x, V0.w, acc0.w);
            acc0.x = fmaf(p0.y, V1.x, acc0.x); acc0.y = fmaf(p0.y, V1.y, acc0.y);
            acc0.z = fmaf(p0.y, V1.z, acc0.z); acc0.w = fmaf(p0.y, V1.w, acc0.w);
            acc0.x = fmaf(p0.z, V2.x, acc0.x); acc0.y = fmaf(p0.z, V2.y, acc0.y);
            acc0.z = fmaf(p0.z, V2.z, acc0.z); acc0.w = fmaf(p0.z, V2.w, acc0.w);
            acc0.x = fmaf(p0.w, V3.x, acc0.x); acc0.y = fmaf(p0.w, V3.y, acc0.y);
            acc0.z = fmaf(p0.w, V3.z, acc0.z); acc0.w = fmaf(p0.w, V3.w, acc0.w);
            acc1.x = fmaf(p1.x, V0.x, acc1.x); acc1.y = fmaf(p1.x, V0.y, acc1.y);
            acc1.z = fmaf(p1.x, V0.z, acc1.z); acc1.w = fmaf(p1.x, V0.w, acc1.w);
            acc1.x = fmaf(p1.y, V1.x, acc1.x); acc1.y = fmaf(p1.y, V1.y, acc1.y);
            acc1.z = fmaf(p1.y, V1.z, acc1.z); acc1.w = fmaf(p1.y, V1.w, acc1.w);
            acc1.x = fmaf(p1.z, V2.x, acc1.x); acc1.y = fmaf(p1.z, V2.y, acc1.y);
            acc1.z = fmaf(p1.z, V2.z, acc1.z); acc1.w = fmaf(p1.z, V2.w, acc1.w);
            acc1.x = fmaf(p1.w, V3.x, acc1.x); acc1.y = fmaf(p1.w, V3.y, acc1.y);
            acc1.z = fmaf(p1.w, V3.z, acc1.z); acc1.w = fmaf(p1.w, V3.w, acc1.w);
        }
        __syncthreads();
    }

    acc0.x += __shfl_xor(acc0.x, 32); acc0.y += __shfl_xor(acc0.y, 32);
    acc0.z += __shfl_xor(acc0.z, 32); acc0.w += __shfl_xor(acc0.w, 32);
    acc1.x += __shfl_xor(acc1.x, 32); acc1.y += __shfl_xor(acc1.y, 32);
    acc1.z += __shfl_xor(acc1.z, 32); acc1.w += __shfl_xor(acc1.w, 32);
    if (ksub == 0) {
        float4* out4 = reinterpret_cast<float4*>(out);
        out4[(size_t)(b * 64 + q0 + 2 * w) * 128 + vt * 32 + v4]     = acc0;
        out4[(size_t)(b * 64 + q0 + 2 * w + 1) * 128 + vt * 32 + v4] = acc1;
    }
}

// ---------------------------------------------------------------------------
extern "C" void kernel_launch(void* const* d_in, const int* in_sizes, int n_in,
                              void* d_out, int out_size, void* d_ws, size_t ws_size,
                              hipStream_t stream) {
    (void)in_sizes; (void)n_in; (void)out_size; (void)ws_size;
    const float* queries    = (const float*)d_in[0];   // [16,64,512]
    const float* keys       = (const float*)d_in[1];   // [16,512,512]
    const float* values     = (const float*)d_in[2];   // [16,512,512]
    const int*   valid_lens = (const int*)d_in[3];     // [16]
    const float* Wq         = (const float*)d_in[4];   // [512,256]
    const float* Wk         = (const float*)d_in[5];   // [512,256]
    const float* Wv         = (const float*)d_in[6];   // [256]
    float* out = (float*)d_out;                        // [16,64,512]

    float* ws     = (float*)d_ws;
    float* Eq     = ws;                         // [1024][256]        1 MB
    float* Ekp    = ws + 262144;                // [16][128][512][2]  8 MB
    float* scores = ws + 262144 + 2097152;      // [16][64][512]      2 MB
    ushort* Wq2T  = (ushort*)(ws + 2883584);    // [256][1536]        0.75 MB
    ushort* Wk2T  = Wq2T + 393216;              // [256][1536]        0.75 MB

    hipLaunchKernelGGL(wprep_kernel, dim3(8, 4, 2), dim3(256), 0, stream,
                       Wq, Wk, Wq2T, Wk2T);
    hipLaunchKernelGGL(mfma_proj_kernel, dim3(288, 2), dim3(256), 0, stream,
                       queries, keys, Wq2T, Wk2T, Eq, Ekp);
    hipLaunchKernelGGL(score_raw_kernel, dim3(4, 8, 16), dim3(256), 0, stream,
                       Eq, Ekp, Wv, valid_lens, scores);
    hipLaunchKernelGGL(pv_kernel, dim3(4, 8, 16), dim3(256), 0, stream,
                       scores, values, out);
}

// Round 12
// 137.090 us; speedup vs baseline: 1.0442x; 1.0442x over previous
//
#include <hip/hip_runtime.h>

// Problem dims: B=16, Q=64, K=512, DQ=DK=DV=512, H=256
#define LOG2E 1.4426950408889634f
#define TWO_LOG2E 2.8853900817779268f

typedef __attribute__((ext_vector_type(8))) short short8;   // bf16x8 MFMA frag
typedef __attribute__((ext_vector_type(4))) float f32x4;    // MFMA acc

__device__ __forceinline__ float e2x(float v) {
    return __builtin_amdgcn_exp2f(v * TWO_LOG2E);   // e^{2v}
}

// Exact fp32 -> (hi,lo) bf16 split, packed.
__device__ __forceinline__ void split2(float x, float y, unsigned& hi, unsigned& lo) {
    unsigned ux = __float_as_uint(x), uy = __float_as_uint(y);
    float hx = __uint_as_float(ux & 0xffff0000u);
    float hy = __uint_as_float(uy & 0xffff0000u);
    unsigned lx = __float_as_uint(x - hx), ly = __float_as_uint(y - hy);
    hi = (ux >> 16) | (uy & 0xffff0000u);
    lo = (lx >> 16) | (ly & 0xffff0000u);
}

// ---------------------------------------------------------------------------
// Kernel 0: W2T split/transposed weights (unchanged)
// ---------------------------------------------------------------------------
__global__ __launch_bounds__(256) void wprep_kernel(const float* __restrict__ Wq,
                                                    const float* __restrict__ Wk,
                                                    ushort* __restrict__ Wq2T,
                                                    ushort* __restrict__ Wk2T) {
    __shared__ float T[64][65];
    const float* W  = blockIdx.z ? Wk : Wq;
    ushort* W2T     = blockIdx.z ? Wk2T : Wq2T;
    const int t  = threadIdx.x;
    const int k0 = blockIdx.x * 64;
    const int n0 = blockIdx.y * 64;
#pragma unroll
    for (int p = 0; p < 4; ++p) {
        int u  = t + p * 256;
        int kk = u >> 4;
        int nf = (u & 15) * 4;
        float4 w = *reinterpret_cast<const float4*>(&W[(size_t)(k0 + kk) * 256 + n0 + nf]);
        T[nf + 0][kk] = w.x; T[nf + 1][kk] = w.y;
        T[nf + 2][kk] = w.z; T[nf + 3][kk] = w.w;
    }
    __syncthreads();
#pragma unroll
    for (int p = 0; p < 4; ++p) {
        int u  = t + p * 256;
        int n  = u >> 4;
        int kf = (u & 15) * 4;
        float a = T[n][kf], b = T[n][kf + 1], c = T[n][kf + 2], d = T[n][kf + 3];
        unsigned h01, l01, h23, l23;
        split2(a, b, h01, l01);
        split2(c, d, h23, l23);
        int kg = k0 + kf;
        ushort* row = W2T + (size_t)(n0 + n) * 1536 + (kg >> 5) * 96 + (kg & 31);
        uint2 hi; hi.x = h01; hi.y = h23;
        uint2 lo; lo.x = l01; lo.y = l23;
        *reinterpret_cast<uint2*>(row)      = hi;
        *reinterpret_cast<uint2*>(row + 32) = hi;
        *reinterpret_cast<uint2*>(row + 64) = lo;
    }
}

// ---------------------------------------------------------------------------
// Kernel 1: fused MFMA projection, n-tile 64 (occupancy 2x: 4.5 blocks/CU).
// Grid (288, 4). Block 32m x 64n, wave-tile 32m x 16n (frags 2m x 1n).
// LDS 18 KB: Ah[32][96] + Ws[64][96].
// ---------------------------------------------------------------------------
__global__ __launch_bounds__(256) void mfma_proj_kernel(const float* __restrict__ queries,
                                                        const float* __restrict__ keys,
                                                        const ushort* __restrict__ Wq2T,
                                                        const ushort* __restrict__ Wk2T,
                                                        float* __restrict__ Eq,
                                                        float* __restrict__ Ekp) {
    __shared__ float smemf[4608];            // 18432 B: Ah(6144) + Ws(12288); reused as Cs
    ushort* Ah = reinterpret_cast<ushort*>(smemf);           // [32 m][96 k']
    ushort* Ws = reinterpret_cast<ushort*>(smemf) + 3072;    // [64 n][96 k']

    const int t    = threadIdx.x;
    const int mt   = blockIdx.x;
    const int Nb   = blockIdx.y * 64;
    const bool isQ = mt < 32;
    const int mloc = (isQ ? mt : mt - 32) * 32;
    const float4* Asrc4 = reinterpret_cast<const float4*>(isQ ? queries : keys)
                        + (size_t)mloc * 128;
    const ushort* W2T = isQ ? Wq2T : Wk2T;

    const int ln15 = t & 15;
    const int q    = (t >> 4) & 3;
    const int w    = t >> 6;
    const int wn   = w * 16;                 // wave n-offset within 64
    const int am   = t >> 3;
    const int ak   = t & 7;

    // B glds: 12288 B/chunk = 3 calls x 4096 B; o = i*4096 + t*16
    const char* gB[3];
#pragma unroll
    for (int i = 0; i < 3; ++i) {
        int o   = i * 4096 + t * 16;
        int row = o / 192;                   // n row 0..63
        int rem = o - row * 192;
        gB[i] = reinterpret_cast<const char*>(W2T) + (size_t)(Nb + row) * 3072 + rem;
    }

    f32x4 acc[2];
    acc[0] = (f32x4)0.0f;
    acc[1] = (f32x4)0.0f;

    float4 ra = Asrc4[(size_t)am * 128 + ak];

    for (int c = 0; c < 16; ++c) {
        __syncthreads();
#pragma unroll
        for (int i = 0; i < 3; ++i) {
            __builtin_amdgcn_global_load_lds(
                reinterpret_cast<const unsigned int*>(gB[i]),
                reinterpret_cast<unsigned int*>(
                    reinterpret_cast<char*>(Ah) + 6144 + i * 4096 + (t >> 6) * 1024),
                16, 0, 0);
            gB[i] += 192;
        }
        {
            unsigned h01, l01, h23, l23;
            split2(ra.x, ra.y, h01, l01);
            split2(ra.z, ra.w, h23, l23);
            uint2 hi; hi.x = h01; hi.y = h23;
            uint2 lo; lo.x = l01; lo.y = l23;
            ushort* row = Ah + am * 96 + ak * 4;
            *reinterpret_cast<uint2*>(row)      = hi;
            *reinterpret_cast<uint2*>(row + 32) = lo;
            *reinterpret_cast<uint2*>(row + 64) = hi;
        }
        if (c < 15) ra = Asrc4[(size_t)am * 128 + (c + 1) * 8 + ak];
        __syncthreads();
#pragma unroll
        for (int s = 0; s < 3; ++s) {
            short8 af[2], bf;
#pragma unroll
            for (int fm = 0; fm < 2; ++fm)
                af[fm] = *reinterpret_cast<const short8*>(
                    Ah + (fm * 16 + ln15) * 96 + s * 32 + q * 8);
            bf = *reinterpret_cast<const short8*>(
                Ws + (wn + ln15) * 96 + s * 32 + q * 8);
#pragma unroll
            for (int fm = 0; fm < 2; ++fm)
                acc[fm] = __builtin_amdgcn_mfma_f32_16x16x32_bf16(
                    af[fm], bf, acc[fm], 0, 0, 0);
        }
    }

    if (isQ) {
#pragma unroll
        for (int fm = 0; fm < 2; ++fm)
#pragma unroll
            for (int r = 0; r < 4; ++r) {
                int row = mloc + fm * 16 + q * 4 + r;
                int col = Nb + wn + ln15;
                Eq[(size_t)row * 256 + col] = e2x(acc[fm][r]);
            }
    } else {
        __syncthreads();
        float (*Cs)[33] = reinterpret_cast<float(*)[33]>(smemf);  // [n 64][m 32]
#pragma unroll
        for (int fm = 0; fm < 2; ++fm)
#pragma unroll
            for (int r = 0; r < 4; ++r) {
                int m_l = fm * 16 + q * 4 + r;
                int n_l = wn + ln15;
                Cs[n_l][m_l] = acc[fm][r];
            }
        __syncthreads();
        const int b      = mloc >> 9;
        const int k0h    = (mloc & 511) >> 1;
        const int h2base = Nb >> 1;
        float4* out4 = reinterpret_cast<float4*>(Ekp);
#pragma unroll
        for (int p = 0; p < 2; ++p) {
            int u   = t + p * 256;           // 0..511
            int h2r = u >> 4;                // 0..31
            int kp  = u & 15;                // 0..15
            int kk  = kp * 2;
            float4 o;
            o.x = e2x(Cs[2 * h2r    ][kk    ]);
            o.y = e2x(Cs[2 * h2r + 1][kk    ]);
            o.z = e2x(Cs[2 * h2r    ][kk + 1]);
            o.w = e2x(Cs[2 * h2r + 1][kk + 1]);
            out4[(size_t)b * 32768 + (size_t)(h2base + h2r) * 256 + k0h + kp] = o;
        }
    }
}

// ---------------------------------------------------------------------------
// Kernel 2: raw masked scores, k-split 64 (occupancy 2x: 4 blocks/CU).
// Block = (64k, 8q, b); grid (8, 8, 16) = 1024. 256 thr = 64 k-lanes x
// 4 h-quarters (32 h2 each); Eq8 + Wv in LDS; partials combined via LDS.
// ---------------------------------------------------------------------------
__global__ __launch_bounds__(256) void score_raw_kernel(
        const float* __restrict__ Eq, const float* __restrict__ Ekp,
        const float* __restrict__ Wv, const int* __restrict__ valid_lens,
        float* __restrict__ scores) {
    __shared__ float Eqs[8][256];     // 8 KB
    __shared__ float Wvs[256];        // 1 KB
    __shared__ float Sh[4][8][64];    // 8 KB
    const int t  = threadIdx.x;
    const int kb = blockIdx.x * 64;
    const int q0 = blockIdx.y * 8;
    const int b  = blockIdx.z;

    const float4* eq4 = reinterpret_cast<const float4*>(Eq + (size_t)(b * 64 + q0) * 256);
#pragma unroll
    for (int i = 0; i < 2; ++i) {
        int u = t + i * 256;          // 0..511: row = u>>6, col4 = u&63
        *reinterpret_cast<float4*>(&Eqs[u >> 6][(u & 63) * 4]) = eq4[u];
    }
    Wvs[t] = Wv[t];
    __syncthreads();

    const int kl = t & 63;            // k_local 0..63
    const int hh = t >> 6;            // h-quarter 0..3
    const float2* ek2 = reinterpret_cast<const float2*>(Ekp)
                      + (size_t)b * 65536 + (size_t)(hh * 32) * 512 + kb + kl;

    float acc[8] = {0.f, 0.f, 0.f, 0.f, 0.f, 0.f, 0.f, 0.f};
#pragma unroll 4
    for (int i = 0; i < 32; ++i) {
        float2 ek = ek2[(size_t)i * 512];
        int h2 = hh * 32 + i;
        float w0 = Wvs[2 * h2], w1 = Wvs[2 * h2 + 1];
#pragma unroll
        for (int q = 0; q < 8; ++q) {
            float e0 = Eqs[q][2 * h2], e1 = Eqs[q][2 * h2 + 1];
            float a0 = fmaf(e0, ek.x, 1.0f);
            float a1 = fmaf(e1, ek.y, 1.0f);
            float d  = a0 * a1;
            float n  = fmaf(w1, a0, w0 * a1);
            acc[q] = fmaf(n, __builtin_amdgcn_rcpf(d), acc[q]);
        }
    }
#pragma unroll
    for (int q = 0; q < 8; ++q) Sh[hh][q][kl] = acc[q];
    __syncthreads();

    const int vl = valid_lens[b];
#pragma unroll
    for (int i = 0; i < 2; ++i) {
        int u = t + i * 256;          // 0..511
        int q = u >> 6, k = u & 63;
        float s = -2.0f * ((Sh[0][q][k] + Sh[1][q][k]) + (Sh[2][q][k] + Sh[3][q][k]));
        if (kb + k >= vl) s = -1e6f;
        scores[(size_t)(b * 64 + q0 + q) * 512 + kb + k] = s;
    }
}

// ---------------------------------------------------------------------------
// Kernel 3: fused softmax + out = P @ values, v-tile 64 (4 blocks/CU).
// Block = (b, 8q, 64v); grid (8, 8, 16) = 1024. Ps[8][516] + Vs[2][32][64]
// (dbuf glds). Lane = (v4 0..15, ksub 0..3); shfl_xor(16,32) combine.
// ---------------------------------------------------------------------------
__global__ __launch_bounds__(256) void pv_kernel(const float* __restrict__ scores,
                                                 const float* __restrict__ values,
                                                 float* __restrict__ out) {
    __shared__ __align__(16) float Ps[8][516];     // 16512 B
    __shared__ __align__(16) float Vs[2][32][64];  // 2 x 8192 B

    const int t  = threadIdx.x;
    const int b  = blockIdx.z;
    const int q0 = blockIdx.y * 8;
    const int vt = blockIdx.x;                     // v-tile: 64 floats = 16 f4

    const float4* sc4 = reinterpret_cast<const float4*>(scores) + (size_t)(b * 64 + q0) * 128;
#pragma unroll
    for (int p = 0; p < 4; ++p) {
        int u  = t + p * 256;
        int qr = u >> 7;
        int c4 = u & 127;
        *reinterpret_cast<float4*>(&Ps[qr][c4 * 4]) = sc4[(size_t)qr * 128 + c4];
    }

    // V staging: chunk = 32 k x 64 v x 4 B = 8 KB = 2 glds x 4096 B.
    // o = i*4096 + t*16 -> k = i*16 + (t>>4), byte-in-row = (t&15)*16.
    const char* vbase = reinterpret_cast<const char*>(values)
                      + ((size_t)b * 512 * 512 + (size_t)vt * 64) * 4
                      + (size_t)(t >> 4) * 2048 + (size_t)(t & 15) * 16;
    char* ldsV0 = reinterpret_cast<char*>(&Vs[0][0][0]) + (t >> 6) * 1024;

    const int lane = t & 63;
    const int w    = t >> 6;                       // wave -> q-pair {2w, 2w+1}
    const int v4   = lane & 15;
    const int ksub = lane >> 4;                    // 0..3

    // issue chunk 0 into buffer 0
#pragma unroll
    for (int i = 0; i < 2; ++i)
        __builtin_amdgcn_global_load_lds(
            reinterpret_cast<const unsigned int*>(vbase + (size_t)i * 32768),
            reinterpret_cast<unsigned int*>(ldsV0 + i * 4096), 16, 0, 0);
    __syncthreads();                               // Ps + chunk0 ready

    // ---- per-wave softmax on own rows ----
#pragma unroll
    for (int rr = 0; rr < 2; ++rr) {
        const int r = 2 * w + rr;
        float v[8];
        float m = -1e30f;
#pragma unroll
        for (int i = 0; i < 8; ++i) { v[i] = Ps[r][lane + i * 64]; m = fmaxf(m, v[i]); }
#pragma unroll
        for (int off = 32; off > 0; off >>= 1) m = fmaxf(m, __shfl_xor(m, off));
        float s = 0.f;
#pragma unroll
        for (int i = 0; i < 8; ++i) {
            v[i] = __builtin_amdgcn_exp2f((v[i] - m) * LOG2E);
            s += v[i];
        }
#pragma unroll
        for (int off = 32; off > 0; off >>= 1) s += __shfl_xor(s, off);
        float inv = 1.0f / s;
#pragma unroll
        for (int i = 0; i < 8; ++i) Ps[r][lane + i * 64] = v[i] * inv;
    }

    float4 acc0 = make_float4(0.f, 0.f, 0.f, 0.f);
    float4 acc1 = make_float4(0.f, 0.f, 0.f, 0.f);

    for (int c = 0; c < 16; ++c) {
        if (c < 15) {
            char* dst = reinterpret_cast<char*>(&Vs[(c + 1) & 1][0][0]) + (t >> 6) * 1024;
            const char* src = vbase + (size_t)(c + 1) * 65536;
#pragma unroll
            for (int i = 0; i < 2; ++i)
                __builtin_amdgcn_global_load_lds(
                    reinterpret_cast<const unsigned int*>(src + (size_t)i * 32768),
                    reinterpret_cast<unsigned int*>(dst + i * 4096), 16, 0, 0);
        }

        const float (*V)[64] = Vs[c & 1];
        const float* pr0 = &Ps[2 * w][c * 32];
        const float* pr1 = &Ps[2 * w + 1][c * 32];
#pragma unroll
        for (int kk = 0; kk < 2; ++kk) {
            int kb = kk * 16 + ksub * 4;
            float4 V0 = *reinterpret_cast<const float4*>(&V[kb + 0][v4 * 4]);
            float4 V1 = *reinterpret_cast<const float4*>(&V[kb + 1][v4 * 4]);
            float4 V2 = *reinterpret_cast<const float4*>(&V[kb + 2][v4 * 4]);
            float4 V3 = *reinterpret_cast<const float4*>(&V[kb + 3][v4 * 4]);
            float4 p0 = *reinterpret_cast<const float4*>(&pr0[kb]);
            float4 p1 = *reinterpret_cast<const float4*>(&pr1[kb]);
            acc0.x = fmaf(p0.x, V0.x, acc0.x); acc0.y = fmaf(p0.x, V0.y, acc0.y);
            acc0.z = fmaf(p0.x, V0.z, acc0.z); acc0.w = fmaf(p0.x, V0.w, acc0.w);
            acc0.x = fmaf(p0.y, V1.x, acc0.x); acc0.y = fmaf(p0.y, V1.y, acc0.y);
            acc0.z = fmaf(p0.y, V1.z, acc0.z); acc0.w = fmaf(p0.y, V1.w, acc0.w);
            acc0.x = fmaf(p0.z, V2.x, acc0.x); acc0.y = fmaf(p0.z, V2.y, acc0.y);
            acc0.z = fmaf(p0.z, V2.z, acc0.z); acc0.w = fmaf(p0.z, V2.w, acc0.w);
            acc0.x = fmaf(p0.w, V3.x, acc0.x); acc0.y = fmaf(p0.w, V3.y, acc0.y);
            acc0.z = fmaf(p0.w, V3.z, acc0.z); acc0.w = fmaf(p0.w, V3.w, acc0.w);
            acc1.x = fmaf(p1.x, V0.x, acc1.x); acc1.y = fmaf(p1.x, V0.y, acc1.y);
            acc1.z = fmaf(p1.x, V0.z, acc1.z); acc1.w = fmaf(p1.x, V0.w, acc1.w);
            acc1.x = fmaf(p1.y, V1.x, acc1.x); acc1.y = fmaf(p1.y, V1.y, acc1.y);
            acc1.z = fmaf(p1.y, V1.z, acc1.z); acc1.w = fmaf(p1.y, V1.w, acc1.w);
            acc1.x = fmaf(p1.z, V2.x, acc1.x); acc1.y = fmaf(p1.z, V2.y, acc1.y);
            acc1.z = fmaf(p1.z, V2.z, acc1.z); acc1.w = fmaf(p1.z, V2.w, acc1.w);
            acc1.x = fmaf(p1.w, V3.x, acc1.x); acc1.y = fmaf(p1.w, V3.y, acc1.y);
            acc1.z = fmaf(p1.w, V3.z, acc1.z); acc1.w = fmaf(p1.w, V3.w, acc1.w);
        }
        __syncthreads();
    }

    // combine 4 ksub partials (butterfly over lane bits 4,5)
#pragma unroll
    for (int off = 16; off <= 32; off <<= 1) {
        acc0.x += __shfl_xor(acc0.x, off); acc0.y += __shfl_xor(acc0.y, off);
        acc0.z += __shfl_xor(acc0.z, off); acc0.w += __shfl_xor(acc0.w, off);
        acc1.x += __shfl_xor(acc1.x, off); acc1.y += __shfl_xor(acc1.y, off);
        acc1.z += __shfl_xor(acc1.z, off); acc1.w += __shfl_xor(acc1.w, off);
    }
    if (ksub == 0) {
        float4* out4 = reinterpret_cast<float4*>(out);
        out4[(size_t)(b * 64 + q0 + 2 * w) * 128 + vt * 16 + v4]     = acc0;
        out4[(size_t)(b * 64 + q0 + 2 * w + 1) * 128 + vt * 16 + v4] = acc1;
    }
}

// ---------------------------------------------------------------------------
extern "C" void kernel_launch(void* const* d_in, const int* in_sizes, int n_in,
                              void* d_out, int out_size, void* d_ws, size_t ws_size,
                              hipStream_t stream) {
    (void)in_sizes; (void)n_in; (void)out_size; (void)ws_size;
    const float* queries    = (const float*)d_in[0];   // [16,64,512]
    const float* keys       = (const float*)d_in[1];   // [16,512,512]
    const float* values     = (const float*)d_in[2];   // [16,512,512]
    const int*   valid_lens = (const int*)d_in[3];     // [16]
    const float* Wq         = (const float*)d_in[4];   // [512,256]
    const float* Wk         = (const float*)d_in[5];   // [512,256]
    const float* Wv         = (const float*)d_in[6];   // [256]
    float* out = (float*)d_out;                        // [16,64,512]

    float* ws     = (float*)d_ws;
    float* Eq     = ws;                         // [1024][256]        1 MB
    float* Ekp    = ws + 262144;                // [16][128][512][2]  8 MB
    float* scores = ws + 262144 + 2097152;      // [16][64][512]      2 MB
    ushort* Wq2T  = (ushort*)(ws + 2883584);    // [256][1536]        0.75 MB
    ushort* Wk2T  = Wq2T + 393216;              // [256][1536]        0.75 MB

    hipLaunchKernelGGL(wprep_kernel, dim3(8, 4, 2), dim3(256), 0, stream,
                       Wq, Wk, Wq2T, Wk2T);
    hipLaunchKernelGGL(mfma_proj_kernel, dim3(288, 4), dim3(256), 0, stream,
                       queries, keys, Wq2T, Wk2T, Eq, Ekp);
    hipLaunchKernelGGL(score_raw_kernel, dim3(8, 8, 16), dim3(256), 0, stream,
                       Eq, Ekp, Wv, valid_lens, scores);
    hipLaunchKernelGGL(pv_kernel, dim3(8, 8, 16), dim3(256), 0, stream,
                       scores, values, out);
}